// Round 8
// baseline (1652.120 us; speedup 1.0000x reference)
//
#include <hip/hip_runtime.h>
#include <math.h>

#define DI __device__ __forceinline__

constexpr int BB = 64;     // batch
constexpr int TT = 128;    // action steps (obs/rewards have TT+1)
constexpr int SS = 512;    // states
constexpr int AA = 16;     // actions
constexpr int OO = 4096;   // observations
constexpr float LOG2PI = 1.8378770664093453f;
constexpr float LOG4096 = 8.317766166719343f;  // log(16*256)

typedef float f32x4 __attribute__((ext_vector_type(4)));

// LDS-only barrier: does NOT drain vmcnt.
DI void lds_barrier() {
    asm volatile("s_waitcnt lgkmcnt(0)\n\ts_barrier" ::: "memory");
}

// ---------------- fp8 e4m3fn converter (RTNE), x in [0, 448) ----------------
DI unsigned int f32_to_e4m3(float x) {
    unsigned int u = __float_as_uint(x);
    unsigned int lsb = (u >> 20) & 1u;
    unsigned int rounded = u + 0x7ffffu + lsb;          // RTNE into 3-bit mantissa
    int e8 = (int)(rounded >> 23) - 120;                // 127 - 7
    unsigned int m3 = (rounded >> 20) & 7u;
    unsigned int norm = ((unsigned int)e8 << 3) | m3;
    int sub = __float2int_rn(x * 512.0f);               // subnormal: multiples of 2^-9
    return (e8 <= 0) ? (unsigned int)sub : norm;
}

// ---------------- reduction helpers (wave64) ----------------
DI float bflyMax(float v) {
#pragma unroll
    for (int off = 32; off; off >>= 1) v = fmaxf(v, __shfl_xor(v, off));
    return v;
}
DI float bflySum(float v) {
#pragma unroll
    for (int off = 32; off; off >>= 1) v += __shfl_xor(v, off);
    return v;
}
DI float halfMax(float v) {
#pragma unroll
    for (int off = 16; off; off >>= 1) v = fmaxf(v, __shfl_xor(v, off));
    return v;
}
DI float halfSum(float v) {
#pragma unroll
    for (int off = 16; off; off >>= 1) v += __shfl_xor(v, off);
    return v;
}

template <int NW>
DI float blockMax(float v, float* wr) {
    v = bflyMax(v);
    const int lane = threadIdx.x & 63, wv = threadIdx.x >> 6;
    if (lane == 0) wr[wv] = v;
    __syncthreads();
    float r = wr[0];
#pragma unroll
    for (int i = 1; i < NW; ++i) r = fmaxf(r, wr[i]);
    __syncthreads();
    return r;
}
template <int NW>
DI float blockSum(float v, float* wr) {
    v = bflySum(v);
    const int lane = threadIdx.x & 63, wv = threadIdx.x >> 6;
    if (lane == 0) wr[wv] = v;
    __syncthreads();
    float r = wr[0];
#pragma unroll
    for (int i = 1; i < NW; ++i) r += wr[i];
    __syncthreads();
    return r;
}

// ---------------- precompute kernels ----------------

// Fused softmax + fp8 quantize (x256) + fragment swizzle into the NEW layout:
// PB byte addr = a*262144 + n*8192 + (kt>>1)*1024 + lane*16 + (kt&1)*8 + j
//   n = 16-col tile (0..31), kt = 32-row k-tile (0..15), lane = MFMA lane,
//   j = byte within fragment; fragment byte j (kt,n,lane) =
//   P[a][kt*32 + (lane>>4)*8 + j][n*16 + (lane&15)] * 256 in fp8 e4m3.
// So in k_main, wave owning ntile n reads ulonglong2 at (ktp*1024 + lane*16):
// .x = fragment for kt=2ktp, .y = fragment for kt=2ktp+1 — 8 coalesced loads
// cover the full k range. Same fragment VALUES as R3-R7 (bit-identical).
__global__ __launch_bounds__(1024) void k_pack(const float* __restrict__ tl,
                                               unsigned char* __restrict__ PB) {
    __shared__ unsigned char lds[16384];
    const int a = blockIdx.x >> 4;
    const int kt = blockIdx.x & 15;
    const int tid = threadIdx.x;
    const int r = tid >> 5;       // 0..31 (row within ktile)
    const int nt = tid & 31;      // 0..31 (16-col tile)
    const int k = kt * 32 + r;
    const float* row = tl + ((size_t)a * SS + k) * SS + nt * 16;

    float x[16];
#pragma unroll
    for (int i = 0; i < 4; ++i) {
        float4 v = ((const float4*)row)[i];
        x[4 * i] = v.x; x[4 * i + 1] = v.y; x[4 * i + 2] = v.z; x[4 * i + 3] = v.w;
    }
    float mx = -INFINITY;
#pragma unroll
    for (int i = 0; i < 16; ++i) mx = fmaxf(mx, x[i]);
    mx = halfMax(mx);
    float e[16];
    float sm = 0.f;
#pragma unroll
    for (int i = 0; i < 16; ++i) { e[i] = __expf(x[i] - mx); sm += e[i]; }
    sm = halfSum(sm);
    const float scale = 256.0f / sm;

    // internal LDS layout (same as R3): (nt>>1)*1024 + lane*16 + (nt&1)*8 + j
    const int base = (nt >> 1) * 1024 + ((r >> 3) * 16) * 16 + (nt & 1) * 8 + (r & 7);
#pragma unroll
    for (int i = 0; i < 16; ++i) {
        lds[base + i * 16] = (unsigned char)f32_to_e4m3(e[i] * scale);
    }
    __syncthreads();

    // copy out to the new (a, n, ktp, lane, kt&1) layout
#pragma unroll
    for (int c = 0; c < 2; ++c) {
        int idx = tid + c * 1024;          // 0..2047
        int n = idx >> 6, lane = idx & 63;
        unsigned long long v =
            *(const unsigned long long*)(lds + (n >> 1) * 1024 + lane * 16 + (n & 1) * 8);
        *(unsigned long long*)(PB + (size_t)a * 262144 + n * 8192 +
                               (kt >> 1) * 1024 + lane * 16 + (kt & 1) * 8) = v;
    }
}

__global__ __launch_bounds__(256) void k_obs_stats(const float* __restrict__ ol,
                                                   float* __restrict__ mo,
                                                   float* __restrict__ lo) {
    __shared__ float wr[4];
    const int s = blockIdx.x;
    const float* in = ol + (size_t)s * OO;
    const int tid = threadIdx.x;
    float mx = -INFINITY;
    for (int i = tid; i < OO; i += 256) mx = fmaxf(mx, in[i]);
    float m = blockMax<4>(mx, wr);
    float sm = 0.f;
    for (int i = tid; i < OO; i += 256) sm += __expf(in[i] - m);
    float sum = blockSum<4>(sm, wr);
    if (tid == 0) { mo[s] = m; lo[s] = __logf(sum); }
}

__global__ __launch_bounds__(256) void k_obsT(const float* __restrict__ ol,
                                              const float* __restrict__ mo,
                                              const float* __restrict__ lo,
                                              float* __restrict__ obsT) {
    __shared__ float tile[64][65];
    const int tO = blockIdx.x % (OO / 64);
    const int tS = blockIdx.x / (OO / 64);
    const int o0 = tO * 64, s0 = tS * 64;
    const int cc = threadIdx.x & 63, rr = threadIdx.x >> 6;
#pragma unroll
    for (int j = 0; j < 16; ++j) {
        int r = rr + j * 4;
        tile[r][cc] = ol[(size_t)(s0 + r) * OO + o0 + cc] - mo[s0 + r] - lo[s0 + r];
    }
    __syncthreads();
#pragma unroll
    for (int j = 0; j < 16; ++j) {
        int r = rr + j * 4;
        obsT[(size_t)(o0 + r) * SS + s0 + cc] = tile[cc][r];
    }
}

__global__ void k_init(unsigned int* cnt) { cnt[threadIdx.x] = 0u; }

// ---------------- main sequential-scan kernel ----------------
// 4 blocks per batch element (256 blocks, 512 threads = 8 waves each).
// Block j of group b owns columns 128j..128j+127 (wave w -> ntile n=8j+w).
// Phase A (lq, lse, fp8-quantize p) is duplicated in all 4 blocks; the GEMV
// streams only 64 KB/step/CU (8 coalesced 16B loads per wave, 32-VGPR burst
// the compiler can actually keep). Results are exchanged via a double-
// buffered LLC-coherent array with a per-group monotone atomic counter
// barrier (device scope; 2 buffers are race-free since skew <= 1 step).
// Per-column accumulation order is identical to R6 -> bit-identical output.
__global__ __launch_bounds__(512, 2) void k_main(
    const float* __restrict__ regime, const int* __restrict__ obs,
    const float* __restrict__ rewards, const float* __restrict__ dones,
    const int* __restrict__ actions, const float* __restrict__ prior_logits,
    const unsigned char* __restrict__ PB, const float* __restrict__ obsT,
    const float* __restrict__ policy_logits, const float* __restrict__ r_mu,
    const float* __restrict__ r_logsig, float* ex, unsigned int* cnt,
    float* __restrict__ out) {
    __shared__ float wrm[8], wrs[8];
    __shared__ unsigned char p8[4 * 144 + 16];  // [quad][16 kt x 8B], 144-pad
    __shared__ float polT_l[AA * SS];           // 32 KB
    __shared__ int obs_l[TT + 1];
    __shared__ float rew_l[TT + 1];
    __shared__ float done_l[TT + 1];
    __shared__ int act_l[TT];

    const int gb = blockIdx.x;     // 0..255
    const int b = gb >> 2;         // batch element
    const int j = gb & 3;          // column-split index
    const int tid = threadIdx.x;
    const int wv = tid >> 6, lane = tid & 63, quad = lane >> 4;
    const int s = tid;
    const int n = j * 8 + wv;      // this wave's 16-col tile (0..31)

    // ---- one-time preloads ----
    if (tid <= TT) {
        obs_l[tid] = obs[tid * BB + b];
        rew_l[tid] = rewards[tid * BB + b];
        done_l[tid] = dones[tid * BB + b];
        if (tid < TT) act_l[tid] = actions[tid * BB + b];
    }
    {   // inline transposed log-softmax policy -> LDS
        const float4* pr4 = (const float4*)(policy_logits + (size_t)s * AA);
        float4 v0 = pr4[0], v1 = pr4[1], v2 = pr4[2], v3 = pr4[3];
        float xv[16] = {v0.x, v0.y, v0.z, v0.w, v1.x, v1.y, v1.z, v1.w,
                        v2.x, v2.y, v2.z, v2.w, v3.x, v3.y, v3.z, v3.w};
        float mx = xv[0];
#pragma unroll
        for (int i = 1; i < 16; ++i) mx = fmaxf(mx, xv[i]);
        float sm = 0.f;
#pragma unroll
        for (int i = 0; i < 16; ++i) sm += __expf(xv[i] - mx);
        float ls = mx + __logf(sm);
#pragma unroll
        for (int a = 0; a < AA; ++a) polT_l[a * SS + s] = xv[a] - ls;
    }
    const float rm = r_mu[s];
    const float rls = r_logsig[s];
    const float inv_sig = __expf(-rls);
    const float reg = regime[b];

    // inline prior log-softmax (its barriers also publish the preloads)
    float px = prior_logits[s];
    {
        float wm0 = bflyMax(px);
        if (lane == 0) wrm[wv] = wm0;
    }
    lds_barrier();
    float pm = wrm[0];
#pragma unroll
    for (int i = 1; i < 8; ++i) pm = fmaxf(pm, wrm[i]);
    {
        float ws0 = bflySum(__expf(px - pm));
        if (lane == 0) wrs[wv] = ws0;
    }
    lds_barrier();
    float psum = wrs[0];
#pragma unroll
    for (int i = 1; i < 8; ++i) psum += wrs[i];
    const float prior_reg = px - pm - __logf(psum);

    // prefetch obsT row for t=0
    float obsv = obsT[(size_t)obs_l[0] * SS + s];

    float lq_reg = 0.f;     // lqprev[s], valid for t >= 1
    float log_prob = 0.f;
    float was_done = 0.f;

    for (int t = 0; t < TT; ++t) {
        const float r = rew_l[t];
        const int a = __builtin_amdgcn_readfirstlane(act_l[t]);
        const float d = done_l[t];
        const float done = fmaxf(was_done, d);

        // ---- burst: 8 coalesced 16B loads = this wave's full k-range ----
        const unsigned char* base = PB + (size_t)a * 262144 + n * 8192 + lane * 16;
        ulonglong2 bf[8];
#pragma unroll
        for (int ktp = 0; ktp < 8; ++ktp)
            bf[ktp] = *(const ulonglong2*)(base + ktp * 1024);
        float obsv_next = obsT[(size_t)obs_l[t + 1] * SS + s];
        __builtin_amdgcn_sched_barrier(0);

        // ---- phase A ----
        float diff = (r - rm) * inv_sig;
        float emis = obsv - 0.5f * diff * diff - rls - 0.5f * LOG2PI;
        float base_in = (t == 0) ? prior_reg : lq_reg;
        float la = polT_l[a * SS + s];
        if (done == 1.0f || reg == 1.0f) la = 0.f;
        float lq = base_in + emis + la;

        float wmax = bflyMax(lq);
        if (lane == 0) wrm[wv] = wmax;
        lds_barrier();  // B1
        float m = wrm[0];
#pragma unroll
        for (int i = 1; i < 8; ++i) m = fmaxf(m, wrm[i]);

        float exv = __expf(lq - m);
        p8[((s >> 3) & 3) * 144 + (s >> 5) * 8 + (s & 7)] =
            (unsigned char)f32_to_e4m3(exv * 16.0f);
        float wsum = bflySum(exv);
        if (lane == 0) wrs[wv] = wsum;
        lds_barrier();  // B2 (publishes p8)
        float sum = wrs[0];
#pragma unroll
        for (int i = 1; i < 8; ++i) sum += wrs[i];
        float lse = m + __logf(sum);
        float lq_orda = lse * (1.0f - was_done);
        if (!isinf(log_prob)) log_prob += lq_orda;
        was_done = done;

        // ---- phase B: 16 MFMAs for this wave's 16 columns ----
        const float basev = m - lq_orda - LOG4096;
        f32x4 acc = {0.f, 0.f, 0.f, 0.f};
#pragma unroll
        for (int kt = 0; kt < 16; ++kt) {
            long af = *(const long long*)(p8 + quad * 144 + kt * 8);
            long bh = (kt & 1) ? (long)bf[kt >> 1].y : (long)bf[kt >> 1].x;
            acc = __builtin_amdgcn_mfma_f32_16x16x32_fp8_fp8(bh, af, acc, 0, 0, 0);
        }
        // write this wave's 16 columns to the exchange buffer (LLC-coherent)
        float* exb = ex + ((size_t)(t & 1) * BB + b) * SS;
        if (lane < 16) {
            __hip_atomic_store(&exb[n * 16 + lane], basev + __logf(acc[0]),
                               __ATOMIC_RELAXED, __HIP_MEMORY_SCOPE_AGENT);
        }
        __syncthreads();  // drains vmcnt: all 128 col-stores of this block done

        // ---- inter-block barrier (per group, monotone counter) ----
        if (tid == 0) {
            __hip_atomic_fetch_add(&cnt[b], 1u, __ATOMIC_RELEASE,
                                   __HIP_MEMORY_SCOPE_AGENT);
            const unsigned target = 4u * (unsigned)(t + 1);
            while (__hip_atomic_load(&cnt[b], __ATOMIC_ACQUIRE,
                                     __HIP_MEMORY_SCOPE_AGENT) < target)
                __builtin_amdgcn_s_sleep(1);
        }
        lds_barrier();
        // read full lqprev (all 512 cols) for next step
        lq_reg = __hip_atomic_load(&exb[s], __ATOMIC_RELAXED,
                                   __HIP_MEMORY_SCOPE_AGENT);
        obsv = obsv_next;
    }

    // final step t = TT (no action term, no transition)
    {
        const float r = rew_l[TT];
        float diff = (r - rm) * inv_sig;
        float emis = obsv - 0.5f * diff * diff - rls - 0.5f * LOG2PI;
        float lq = lq_reg + emis;
        float wmax = bflyMax(lq);
        if (lane == 0) wrm[wv] = wmax;
        lds_barrier();
        float m = wrm[0];
#pragma unroll
        for (int i = 1; i < 8; ++i) m = fmaxf(m, wrm[i]);
        float wsum = bflySum(__expf(lq - m));
        if (lane == 0) wrs[wv] = wsum;
        lds_barrier();
        float sum = wrs[0];
#pragma unroll
        for (int i = 1; i < 8; ++i) sum += wrs[i];
        float lse = m + __logf(sum);
        float lq_ord = lse * (1.0f - was_done);
        if (!isinf(log_prob)) log_prob += lq_ord;
    }

    if (j == 0 && tid == 0) out[b] = log_prob;
}

// ---------------- launch ----------------
extern "C" void kernel_launch(void* const* d_in, const int* in_sizes, int n_in,
                              void* d_out, int out_size, void* d_ws, size_t ws_size,
                              hipStream_t stream) {
    const float* regime = (const float*)d_in[0];
    const int* obs = (const int*)d_in[1];
    const float* rewards = (const float*)d_in[2];
    const float* dones = (const float*)d_in[3];
    const int* actions = (const int*)d_in[4];
    const float* prior_logits = (const float*)d_in[5];
    const float* trans_logits = (const float*)d_in[6];
    const float* obs_logits = (const float*)d_in[7];
    const float* policy_logits = (const float*)d_in[8];
    const float* r_mu = (const float*)d_in[9];
    const float* r_logsig = (const float*)d_in[10];
    float* out = (float*)d_out;

    char* ws = (char*)d_ws;
    unsigned char* PB = (unsigned char*)ws;                    // A*S*S fp8 = 4 MB
    float* obsT = (float*)(ws + (size_t)AA * SS * SS);         // O*S fp32 = 8 MB
    float* mo = (float*)(ws + (size_t)AA * SS * SS + (size_t)OO * SS * 4);  // S
    float* lo = mo + SS;                                       // S
    unsigned int* cnt = (unsigned int*)(lo + SS);              // 64
    float* ex = (float*)(cnt + 64);                            // 2*B*S = 256 KB

    k_init<<<1, 64, 0, stream>>>(cnt);
    k_pack<<<256, 1024, 0, stream>>>(trans_logits, PB);
    k_obs_stats<<<SS, 256, 0, stream>>>(obs_logits, mo, lo);
    k_obsT<<<(OO / 64) * (SS / 64), 256, 0, stream>>>(obs_logits, mo, lo, obsT);
    k_main<<<BB * 4, 512, 0, stream>>>(regime, obs, rewards, dones, actions,
                                       prior_logits, PB, obsT, policy_logits,
                                       r_mu, r_logsig, ex, cnt, out);
}

// Round 9
// 539.241 us; speedup vs baseline: 3.0638x; 3.0638x over previous
//
#include <hip/hip_runtime.h>
#include <math.h>

#define DI __device__ __forceinline__

constexpr int BB = 64;     // batch
constexpr int TT = 128;    // action steps (obs/rewards have TT+1)
constexpr int SS = 512;    // states
constexpr int AA = 16;     // actions
constexpr int OO = 4096;   // observations
constexpr float LOG2PI = 1.8378770664093453f;
constexpr float LOG4096 = 8.317766166719343f;  // log(16*256)

typedef float f32x4 __attribute__((ext_vector_type(4)));

// LDS-only barrier: does NOT drain vmcnt (in-flight DMA survives).
DI void lds_barrier() {
    asm volatile("s_waitcnt lgkmcnt(0)\n\ts_barrier" ::: "memory");
}

// async global->LDS DMA: 64 lanes x 16 B = 1 KB per instruction.
// lds dest = wave-uniform base + lane*16; g is the per-lane source address.
typedef __attribute__((address_space(3))) unsigned int as3_u32;
typedef __attribute__((address_space(1))) const unsigned int as1_u32;
DI void dma1k(const unsigned char* g, unsigned char* l) {
    __builtin_amdgcn_global_load_lds((as1_u32*)g, (as3_u32*)l, 16, 0, 0);
}

// ---------------- fp8 e4m3fn converter (RTNE), x in [0, 448) ----------------
DI unsigned int f32_to_e4m3(float x) {
    unsigned int u = __float_as_uint(x);
    unsigned int lsb = (u >> 20) & 1u;
    unsigned int rounded = u + 0x7ffffu + lsb;          // RTNE into 3-bit mantissa
    int e8 = (int)(rounded >> 23) - 120;                // 127 - 7
    unsigned int m3 = (rounded >> 20) & 7u;
    unsigned int norm = ((unsigned int)e8 << 3) | m3;
    int sub = __float2int_rn(x * 512.0f);               // subnormal: multiples of 2^-9
    return (e8 <= 0) ? (unsigned int)sub : norm;
}

// ---------------- reduction helpers (wave64) ----------------
DI float bflyMax(float v) {
#pragma unroll
    for (int off = 32; off; off >>= 1) v = fmaxf(v, __shfl_xor(v, off));
    return v;
}
DI float bflySum(float v) {
#pragma unroll
    for (int off = 32; off; off >>= 1) v += __shfl_xor(v, off);
    return v;
}
DI float halfMax(float v) {
#pragma unroll
    for (int off = 16; off; off >>= 1) v = fmaxf(v, __shfl_xor(v, off));
    return v;
}
DI float halfSum(float v) {
#pragma unroll
    for (int off = 16; off; off >>= 1) v += __shfl_xor(v, off);
    return v;
}

template <int NW>
DI float blockMax(float v, float* wr) {
    v = bflyMax(v);
    const int lane = threadIdx.x & 63, wv = threadIdx.x >> 6;
    if (lane == 0) wr[wv] = v;
    __syncthreads();
    float r = wr[0];
#pragma unroll
    for (int i = 1; i < NW; ++i) r = fmaxf(r, wr[i]);
    __syncthreads();
    return r;
}
template <int NW>
DI float blockSum(float v, float* wr) {
    v = bflySum(v);
    const int lane = threadIdx.x & 63, wv = threadIdx.x >> 6;
    if (lane == 0) wr[wv] = v;
    __syncthreads();
    float r = wr[0];
#pragma unroll
    for (int i = 1; i < NW; ++i) r += wr[i];
    __syncthreads();
    return r;
}

// ---------------- precompute kernels ----------------

// Fused softmax + fp8 quantize (x256) + MFMA-B-fragment swizzle (R3 layout).
// PB byte addr = (a*16 + kt)*16384 + ntp*1024 + lane*16 + (nt&1)*8 + j
// fragment byte j of (kt, nt, lane) = P[a][kt*32 + (lane>>4)*8 + j][nt*16 + (lane&15)]*256
__global__ __launch_bounds__(1024) void k_pack(const float* __restrict__ tl,
                                               unsigned char* __restrict__ PB) {
    __shared__ unsigned char lds[16384];
    const int a = blockIdx.x >> 4;
    const int kt = blockIdx.x & 15;
    const int tid = threadIdx.x;
    const int r = tid >> 5;       // 0..31
    const int nt = tid & 31;      // 0..31
    const int k = kt * 32 + r;
    const float* row = tl + ((size_t)a * SS + k) * SS + nt * 16;

    float x[16];
#pragma unroll
    for (int i = 0; i < 4; ++i) {
        float4 v = ((const float4*)row)[i];
        x[4 * i] = v.x; x[4 * i + 1] = v.y; x[4 * i + 2] = v.z; x[4 * i + 3] = v.w;
    }
    float mx = -INFINITY;
#pragma unroll
    for (int i = 0; i < 16; ++i) mx = fmaxf(mx, x[i]);
    mx = halfMax(mx);   // row lives in one 32-lane half
    float e[16];
    float sm = 0.f;
#pragma unroll
    for (int i = 0; i < 16; ++i) { e[i] = __expf(x[i] - mx); sm += e[i]; }
    sm = halfSum(sm);
    const float scale = 256.0f / sm;

    const int base = (nt >> 1) * 1024 + ((r >> 3) * 16) * 16 + (nt & 1) * 8 + (r & 7);
#pragma unroll
    for (int i = 0; i < 16; ++i) {
        lds[base + i * 16] = (unsigned char)f32_to_e4m3(e[i] * scale);
    }
    __syncthreads();

    ulonglong2* dst = (ulonglong2*)(PB + (size_t)(a * 16 + kt) * 16384);
    dst[tid] = ((const ulonglong2*)lds)[tid];
}

__global__ __launch_bounds__(256) void k_obs_stats(const float* __restrict__ ol,
                                                   float* __restrict__ mo,
                                                   float* __restrict__ lo) {
    __shared__ float wr[4];
    const int s = blockIdx.x;
    const float* in = ol + (size_t)s * OO;
    const int tid = threadIdx.x;
    float mx = -INFINITY;
    for (int i = tid; i < OO; i += 256) mx = fmaxf(mx, in[i]);
    float m = blockMax<4>(mx, wr);
    float sm = 0.f;
    for (int i = tid; i < OO; i += 256) sm += __expf(in[i] - m);
    float sum = blockSum<4>(sm, wr);
    if (tid == 0) { mo[s] = m; lo[s] = __logf(sum); }
}

__global__ __launch_bounds__(256) void k_obsT(const float* __restrict__ ol,
                                              const float* __restrict__ mo,
                                              const float* __restrict__ lo,
                                              float* __restrict__ obsT) {
    __shared__ float tile[64][65];
    const int tO = blockIdx.x % (OO / 64);
    const int tS = blockIdx.x / (OO / 64);
    const int o0 = tO * 64, s0 = tS * 64;
    const int cc = threadIdx.x & 63, rr = threadIdx.x >> 6;
#pragma unroll
    for (int j = 0; j < 16; ++j) {
        int r = rr + j * 4;
        tile[r][cc] = ol[(size_t)(s0 + r) * OO + o0 + cc] - mo[s0 + r] - lo[s0 + r];
    }
    __syncthreads();
#pragma unroll
    for (int j = 0; j < 16; ++j) {
        int r = rr + j * 4;
        obsT[(size_t)(o0 + r) * SS + s0 + cc] = tile[cc][r];
    }
}

// ---------------- main sequential-scan kernel ----------------
// one block per batch element, 512 threads = 8 waves, thread == state.
// Per-step P staging via global_load_lds DMA into a ring of 3 x 16 KB LDS
// buffers (1 ktile each, per-wave-private slices): 2 chunks always in
// flight (32 KB >> BW*latency), no VGPR landing zone, explicit vmcnt(N)
// gates each ktile's ds_read+MFMA. Numerically identical to R6.
__global__ __launch_bounds__(512) void k_main(
    const float* __restrict__ regime, const int* __restrict__ obs,
    const float* __restrict__ rewards, const float* __restrict__ dones,
    const int* __restrict__ actions, const float* __restrict__ prior_logits,
    const unsigned char* __restrict__ PB, const float* __restrict__ obsT,
    const float* __restrict__ policy_logits, const float* __restrict__ r_mu,
    const float* __restrict__ r_logsig, float* __restrict__ out) {
    __shared__ unsigned char stage[3 * 16384];  // ring: [buf][wave][npp][lane*16]
    __shared__ float wrm[8], wrs[8];
    __shared__ unsigned char p8[4 * 144 + 16];  // [quad][16 kt x 8B], 144-pad
    __shared__ float lqprev[SS];
    __shared__ int obs_l[TT + 1];
    __shared__ float rew_l[TT + 1];
    __shared__ float done_l[TT + 1];
    __shared__ int act_l[TT];

    const int b = blockIdx.x;
    const int tid = threadIdx.x;
    const int wv = tid >> 6, lane = tid & 63, quad = lane >> 4;
    const int s = tid;

    // ---- one-time preloads ----
    if (tid <= TT) {
        obs_l[tid] = obs[tid * BB + b];
        rew_l[tid] = rewards[tid * BB + b];
        done_l[tid] = dones[tid * BB + b];
        if (tid < TT) act_l[tid] = actions[tid * BB + b];
    }
    // transposed log-softmax policy -> 16 registers per thread
    float la16[16];
    {
        const float4* pr4 = (const float4*)(policy_logits + (size_t)s * AA);
        float4 v0 = pr4[0], v1 = pr4[1], v2 = pr4[2], v3 = pr4[3];
        la16[0] = v0.x; la16[1] = v0.y; la16[2] = v0.z; la16[3] = v0.w;
        la16[4] = v1.x; la16[5] = v1.y; la16[6] = v1.z; la16[7] = v1.w;
        la16[8] = v2.x; la16[9] = v2.y; la16[10] = v2.z; la16[11] = v2.w;
        la16[12] = v3.x; la16[13] = v3.y; la16[14] = v3.z; la16[15] = v3.w;
        float mx = la16[0];
#pragma unroll
        for (int i = 1; i < 16; ++i) mx = fmaxf(mx, la16[i]);
        float sm = 0.f;
#pragma unroll
        for (int i = 0; i < 16; ++i) sm += __expf(la16[i] - mx);
        float ls = mx + __logf(sm);
#pragma unroll
        for (int i = 0; i < 16; ++i) la16[i] -= ls;
    }
    const float rm = r_mu[s];
    const float rls = r_logsig[s];
    const float inv_sig = __expf(-rls);
    const float reg = regime[b];

    // inline prior log-softmax (its barriers also publish the preloads)
    float px = prior_logits[s];
    {
        float wm0 = bflyMax(px);
        if (lane == 0) wrm[wv] = wm0;
    }
    lds_barrier();
    float pm = wrm[0];
#pragma unroll
    for (int i = 1; i < 8; ++i) pm = fmaxf(pm, wrm[i]);
    {
        float ws0 = bflySum(__expf(px - pm));
        if (lane == 0) wrs[wv] = ws0;
    }
    lds_barrier();
    float psum = wrs[0];
#pragma unroll
    for (int i = 1; i < 8; ++i) psum += wrs[i];
    const float prior_reg = px - pm - __logf(psum);

    // prefetch obsT row for t=0
    float obsv = obsT[(size_t)obs_l[0] * SS + s];

    float log_prob = 0.f;
    float was_done = 0.f;

    for (int t = 0; t < TT; ++t) {
        const float r = rew_l[t];
        const int a = __builtin_amdgcn_readfirstlane(act_l[t]);
        const float d = done_l[t];
        const float done = fmaxf(was_done, d);

        const unsigned char* PBa = PB + (size_t)a * (16 * 16384);
        unsigned char* mystage = stage + wv * 2048;

        // DMA ktiles 0..2 into ring buffers 0..2 (2 insts/wave/ktile)
#pragma unroll
        for (int c = 0; c < 3; ++c) {
            const unsigned char* g = PBa + c * 16384 + (2 * wv) * 1024 + lane * 16;
            unsigned char* l = mystage + c * 16384;
            dma1k(g, l);
            dma1k(g + 1024, l + 1024);
        }
        asm volatile("" ::: "memory");  // pin: obsv load issues AFTER the DMAs
        float obsv_next = obsT[(size_t)obs_l[t + 1] * SS + s];
        asm volatile("" ::: "memory");

        // ---- phase A (no global loads here: vmcnt counts stay exact) ----
        float diff = (r - rm) * inv_sig;
        float emis = obsv - 0.5f * diff * diff - rls - 0.5f * LOG2PI;
        float base_in = (t == 0) ? prior_reg : lqprev[s];
        float la = la16[0];
#pragma unroll
        for (int i = 1; i < 16; ++i) la = (a == i) ? la16[i] : la;
        if (done == 1.0f || reg == 1.0f) la = 0.f;
        float lq = base_in + emis + la;

        float wmax = bflyMax(lq);
        if (lane == 0) wrm[wv] = wmax;
        lds_barrier();  // B1
        float m = wrm[0];
#pragma unroll
        for (int i = 1; i < 8; ++i) m = fmaxf(m, wrm[i]);

        float exv = __expf(lq - m);
        p8[((s >> 3) & 3) * 144 + (s >> 5) * 8 + (s & 7)] =
            (unsigned char)f32_to_e4m3(exv * 16.0f);
        float wsum = bflySum(exv);
        if (lane == 0) wrs[wv] = wsum;
        lds_barrier();  // B2 (publishes p8)
        float sum = wrs[0];
#pragma unroll
        for (int i = 1; i < 8; ++i) sum += wrs[i];
        float lse = m + __logf(sum);
        float lq_orda = lse * (1.0f - was_done);
        if (!isinf(log_prob)) log_prob += lq_orda;
        was_done = done;

        // ---- phase B: ring-pipelined ktiles; wave owns cols 64wv..64wv+63 ----
        const float basev = m - lq_orda - LOG4096;
        f32x4 acc0 = {0.f, 0.f, 0.f, 0.f};
        f32x4 acc1 = {0.f, 0.f, 0.f, 0.f};
        f32x4 acc2 = {0.f, 0.f, 0.f, 0.f};
        f32x4 acc3 = {0.f, 0.f, 0.f, 0.f};

        // wait schedule (issue order: D0 D1 D2 obsv, then D(c+3) after chunk c):
        // c=0..2: vmcnt(5); c=3..13: vmcnt(4); c=14: vmcnt(2); c=15: vmcnt(0)
#define CHUNK(c, WN)                                                            \
        {                                                                       \
            asm volatile("s_waitcnt vmcnt(" #WN ")" ::: "memory");              \
            const unsigned char* sb = mystage + ((c) % 3) * 16384 + lane * 16;  \
            ulonglong2 f0 = *(const ulonglong2*)(sb);                           \
            ulonglong2 f1 = *(const ulonglong2*)(sb + 1024);                    \
            long af = *(const long long*)(p8 + quad * 144 + (c) * 8);           \
            acc0 = __builtin_amdgcn_mfma_f32_16x16x32_fp8_fp8((long)f0.x, af, acc0, 0, 0, 0); \
            acc1 = __builtin_amdgcn_mfma_f32_16x16x32_fp8_fp8((long)f0.y, af, acc1, 0, 0, 0); \
            acc2 = __builtin_amdgcn_mfma_f32_16x16x32_fp8_fp8((long)f1.x, af, acc2, 0, 0, 0); \
            acc3 = __builtin_amdgcn_mfma_f32_16x16x32_fp8_fp8((long)f1.y, af, acc3, 0, 0, 0); \
            if ((c) + 3 < 16) {                                                 \
                asm volatile("s_waitcnt lgkmcnt(0)" ::: "memory");              \
                const unsigned char* g = PBa + ((c) + 3) * 16384 + (2 * wv) * 1024 + lane * 16; \
                unsigned char* l = mystage + ((c) % 3) * 16384;                 \
                dma1k(g, l);                                                    \
                dma1k(g + 1024, l + 1024);                                      \
            }                                                                   \
        }
        CHUNK(0, 5)  CHUNK(1, 5)  CHUNK(2, 5)  CHUNK(3, 4)
        CHUNK(4, 4)  CHUNK(5, 4)  CHUNK(6, 4)  CHUNK(7, 4)
        CHUNK(8, 4)  CHUNK(9, 4)  CHUNK(10, 4) CHUNK(11, 4)
        CHUNK(12, 4) CHUNK(13, 4) CHUNK(14, 2) CHUNK(15, 0)
#undef CHUNK

        if (lane < 16) {
            lqprev[wv * 64 + lane]      = basev + __logf(acc0[0]);
            lqprev[wv * 64 + 16 + lane] = basev + __logf(acc1[0]);
            lqprev[wv * 64 + 32 + lane] = basev + __logf(acc2[0]);
            lqprev[wv * 64 + 48 + lane] = basev + __logf(acc3[0]);
        }
        lds_barrier();  // B3
        obsv = obsv_next;
    }

    // final step t = TT (no action term, no transition)
    {
        const float r = rew_l[TT];
        float diff = (r - rm) * inv_sig;
        float emis = obsv - 0.5f * diff * diff - rls - 0.5f * LOG2PI;
        float lq = lqprev[s] + emis;
        float wmax = bflyMax(lq);
        if (lane == 0) wrm[wv] = wmax;
        lds_barrier();
        float m = wrm[0];
#pragma unroll
        for (int i = 1; i < 8; ++i) m = fmaxf(m, wrm[i]);
        float wsum = bflySum(__expf(lq - m));
        if (lane == 0) wrs[wv] = wsum;
        lds_barrier();
        float sum = wrs[0];
#pragma unroll
        for (int i = 1; i < 8; ++i) sum += wrs[i];
        float lse = m + __logf(sum);
        float lq_ord = lse * (1.0f - was_done);
        if (!isinf(log_prob)) log_prob += lq_ord;
    }

    if (tid == 0) out[b] = log_prob;
}

// ---------------- launch ----------------
extern "C" void kernel_launch(void* const* d_in, const int* in_sizes, int n_in,
                              void* d_out, int out_size, void* d_ws, size_t ws_size,
                              hipStream_t stream) {
    const float* regime = (const float*)d_in[0];
    const int* obs = (const int*)d_in[1];
    const float* rewards = (const float*)d_in[2];
    const float* dones = (const float*)d_in[3];
    const int* actions = (const int*)d_in[4];
    const float* prior_logits = (const float*)d_in[5];
    const float* trans_logits = (const float*)d_in[6];
    const float* obs_logits = (const float*)d_in[7];
    const float* policy_logits = (const float*)d_in[8];
    const float* r_mu = (const float*)d_in[9];
    const float* r_logsig = (const float*)d_in[10];
    float* out = (float*)d_out;

    char* ws = (char*)d_ws;
    unsigned char* PB = (unsigned char*)ws;                    // A*S*S fp8 = 4 MB
    float* obsT = (float*)(ws + (size_t)AA * SS * SS);         // O*S fp32 = 8 MB
    float* mo = (float*)(ws + (size_t)AA * SS * SS + (size_t)OO * SS * 4);  // S
    float* lo = mo + SS;                                       // S

    k_pack<<<256, 1024, 0, stream>>>(trans_logits, PB);
    k_obs_stats<<<SS, 256, 0, stream>>>(obs_logits, mo, lo);
    k_obsT<<<(OO / 64) * (SS / 64), 256, 0, stream>>>(obs_logits, mo, lo, obsT);
    k_main<<<BB, 512, 0, stream>>>(regime, obs, rewards, dones, actions, prior_logits,
                                   PB, obsT, policy_logits, r_mu, r_logsig, out);
}